// Round 5
// baseline (549.192 us; speedup 1.0000x reference)
//
#include <hip/hip_runtime.h>

#define CH 128
#define OUTC 10
#define NB 256            // buckets (dst >> 9), only ceil(N/512) used
#define BCAP 10240        // per-bucket pair capacity (avg ~8192, >22 sigma margin)
#define PCHUNK 2048       // edges per partition block

typedef __attribute__((ext_vector_type(8))) short short8;
typedef __attribute__((ext_vector_type(4))) float f32x4;

// ---------------------------------------------------------------- helpers

__device__ inline unsigned short f2bf(float f) {
    unsigned u = __builtin_bit_cast(unsigned, f);
    u += 0x7fffu + ((u >> 16) & 1u);   // RNE
    return (unsigned short)(u >> 16);
}
__device__ inline float bflo(unsigned u) { return __builtin_bit_cast(float, u << 16); }
__device__ inline float bfhi(unsigned u) { return __builtin_bit_cast(float, u & 0xffff0000u); }

// ---------------------------------------------------------------- prep: x -> bf16

__global__ void convert_x_kernel(const float4* __restrict__ x4, uint2* __restrict__ xb, int n4) {
    int i = blockIdx.x * 256 + threadIdx.x;
    if (i < n4) {
        float4 v = x4[i];
        uint2 o;
        o.x = (unsigned)f2bf(v.x) | ((unsigned)f2bf(v.y) << 16);
        o.y = (unsigned)f2bf(v.z) | ((unsigned)f2bf(v.w) << 16);
        xb[i] = o;
    }
}

// ---------------------------------------------------------------- prep: weights -> bf16 transposed (wT[n][k])

struct WPtrs { const float* s[6]; unsigned short* d[6]; };

__global__ void transpose_w_kernel(WPtrs p) {
    int m = blockIdx.y;
    int i = blockIdx.x * 256 + threadIdx.x;
    int k = i >> 7;
    int nn = i & 127;
    p.d[m][nn * CH + k] = f2bf(p.s[m][i]);
}

// ---------------------------------------------------------------- CSR build, phase 1: partition edges into buckets
// pairs[b*BCAP + pos] = (dstLocal << 17) | src   (src < 2^17, dstLocal < 512)

__global__ void partition_kernel(const int* __restrict__ src, const int* __restrict__ dst,
                                 int* __restrict__ bucketCnt, unsigned* __restrict__ pairs, int E) {
    __shared__ int hist[NB];
    __shared__ int base[NB];
    __shared__ int cur[NB];
    int tid = threadIdx.x;       // 256
    int e0 = blockIdx.x * PCHUNK;

    hist[tid] = 0;
    __syncthreads();
    #pragma unroll
    for (int i = 0; i < PCHUNK / 256; ++i) {
        int e = e0 + tid + i * 256;
        if (e < E) atomicAdd(&hist[dst[e] >> 9], 1);
    }
    __syncthreads();
    {
        int c = hist[tid];
        base[tid] = (c > 0) ? atomicAdd(&bucketCnt[tid], c) : 0;
        cur[tid] = 0;
    }
    __syncthreads();
    #pragma unroll
    for (int i = 0; i < PCHUNK / 256; ++i) {
        int e = e0 + tid + i * 256;
        if (e < E) {
            int d = dst[e];
            int bkt = d >> 9;
            int p = base[bkt] + atomicAdd(&cur[bkt], 1);
            if (p < BCAP)
                pairs[bkt * BCAP + p] = ((unsigned)(d & 511) << 17) | (unsigned)src[e];
        }
    }
}

// exclusive scan of 256 bucket counts (bucket order == node order)
__global__ void scan_buckets_kernel(const int* __restrict__ cnt, int* __restrict__ base) {
    __shared__ int sm[NB];
    int tid = threadIdx.x;
    sm[tid] = cnt[tid];
    __syncthreads();
    for (int off = 1; off < NB; off <<= 1) {
        int t = (tid >= off) ? sm[tid - off] : 0;
        __syncthreads();
        sm[tid] += t;
        __syncthreads();
    }
    base[tid] = sm[tid] - cnt[tid];
}

// ---------------------------------------------------------------- CSR build, phase 2: per-bucket local build (coalesced out)

__launch_bounds__(256)
__global__ void build_csr_kernel(const unsigned* __restrict__ pairs, const int* __restrict__ bucketCnt,
                                 const int* __restrict__ bucketBase,
                                 int* __restrict__ offs, int* __restrict__ csr, int N) {
    __shared__ int ldeg[512];
    __shared__ int s0[512], s1[512];
    __shared__ int lexc[512];
    __shared__ int lcur[512];
    __shared__ int lcsr[BCAP];

    int b = blockIdx.x;
    int node0 = b << 9;
    if (node0 >= N) return;
    int nLocal = min(512, N - node0);
    int cnt = min(bucketCnt[b], BCAP);
    int gbase = bucketBase[b];
    int tid = threadIdx.x;   // 256

    for (int i = tid; i < 512; i += 256) ldeg[i] = 0;
    __syncthreads();
    for (int i = tid; i < cnt; i += 256)
        atomicAdd(&ldeg[pairs[b * BCAP + i] >> 17], 1);
    __syncthreads();

    for (int i = tid; i < 512; i += 256) s0[i] = ldeg[i];
    __syncthreads();
    int* sp = s0; int* dp = s1;
    for (int off = 1; off < 512; off <<= 1) {
        for (int i = tid; i < 512; i += 256)
            dp[i] = sp[i] + ((i >= off) ? sp[i - off] : 0);
        __syncthreads();
        int* t = sp; sp = dp; dp = t;
    }
    for (int i = tid; i < 512; i += 256) {
        int ex = sp[i] - ldeg[i];
        lexc[i] = ex;
        lcur[i] = ex;
    }
    __syncthreads();

    for (int i = tid; i < cnt; i += 256) {
        unsigned w = pairs[b * BCAP + i];
        int p = atomicAdd(&lcur[w >> 17], 1);
        lcsr[p] = (int)(w & 0x1ffffu);
    }
    __syncthreads();

    for (int i = tid; i < cnt; i += 256) csr[gbase + i] = lcsr[i];
    for (int i = tid; i < nLocal; i += 256) offs[node0 + i] = gbase + lexc[i];
    if (tid == 0 && node0 + nLocal == N) offs[N] = gbase + cnt;
}

// ---------------------------------------------------------------- fused GIN layer:
//   gather (z = h + sum h[src]) -> LDS -> MFMA MLP -> [relu | pool-epilogue]
// 64 rows/block, 256 threads (4 waves). LDS pitch 136 bf16.

#define PQ 136
#define BM 64

__launch_bounds__(256, 3)
__global__ void gin_layer_kernel(const uint4* __restrict__ h4,        // input h (bf16, 16 uint4/row)
                                 const int* __restrict__ offs, const int* __restrict__ csr,
                                 const unsigned short* __restrict__ w1t, const float* __restrict__ b1,
                                 const unsigned short* __restrict__ w2t, const float* __restrict__ b2,
                                 unsigned short* __restrict__ hout,
                                 const int* __restrict__ batch, float* __restrict__ pooled,
                                 int n, int relu_out, int do_pool) {
    __shared__ __align__(16) unsigned short zs[BM * PQ];
    __shared__ __align__(16) unsigned short ws[CH * PQ];

    int tid = threadIdx.x;
    int row0 = blockIdx.x * BM;
    int wv = tid >> 6;
    int lane = tid & 63;
    int lm = lane & 15;
    int lq = lane >> 4;

    // stage w1T while gathering
    for (int i = tid; i < CH * 16; i += 256) {
        int r = i >> 4, c = i & 15;
        *(uint4*)((char*)ws + r * (PQ * 2) + c * 16) = ((const uint4*)w1t)[i];
    }

    // ---- gather phase: z rows straight into LDS (fp32 accum -> bf16)
    {
        int gl = tid & 15;       // lane within 16-lane group (one uint4 = 8 ch)
        int grp = tid >> 4;      // 0..15
        #pragma unroll
        for (int it = 0; it < BM / 16; ++it) {
            int rr = grp + 16 * it;
            int node = row0 + rr;
            uint4 o = make_uint4(0, 0, 0, 0);
            if (node < n) {
                int beg = offs[node], end = offs[node + 1];
                float a[8];
                uint4 self = h4[node * 16 + gl];
                a[0] = bflo(self.x); a[1] = bfhi(self.x);
                a[2] = bflo(self.y); a[3] = bfhi(self.y);
                a[4] = bflo(self.z); a[5] = bfhi(self.z);
                a[6] = bflo(self.w); a[7] = bfhi(self.w);
                int e = beg;
                for (; e + 2 <= end; e += 2) {
                    int s0 = csr[e], s1 = csr[e + 1];
                    uint4 v0 = h4[s0 * 16 + gl];
                    uint4 v1 = h4[s1 * 16 + gl];
                    a[0] += bflo(v0.x); a[1] += bfhi(v0.x);
                    a[2] += bflo(v0.y); a[3] += bfhi(v0.y);
                    a[4] += bflo(v0.z); a[5] += bfhi(v0.z);
                    a[6] += bflo(v0.w); a[7] += bfhi(v0.w);
                    a[0] += bflo(v1.x); a[1] += bfhi(v1.x);
                    a[2] += bflo(v1.y); a[3] += bfhi(v1.y);
                    a[4] += bflo(v1.z); a[5] += bfhi(v1.z);
                    a[6] += bflo(v1.w); a[7] += bfhi(v1.w);
                }
                if (e < end) {
                    uint4 v = h4[csr[e] * 16 + gl];
                    a[0] += bflo(v.x); a[1] += bfhi(v.x);
                    a[2] += bflo(v.y); a[3] += bfhi(v.y);
                    a[4] += bflo(v.z); a[5] += bfhi(v.z);
                    a[6] += bflo(v.w); a[7] += bfhi(v.w);
                }
                o.x = (unsigned)f2bf(a[0]) | ((unsigned)f2bf(a[1]) << 16);
                o.y = (unsigned)f2bf(a[2]) | ((unsigned)f2bf(a[3]) << 16);
                o.z = (unsigned)f2bf(a[4]) | ((unsigned)f2bf(a[5]) << 16);
                o.w = (unsigned)f2bf(a[6]) | ((unsigned)f2bf(a[7]) << 16);
            }
            *(uint4*)((char*)zs + rr * (PQ * 2) + gl * 16) = o;
        }
    }
    __syncthreads();

    // ---- matmul 1: t = relu(z @ w1 + b1)
    f32x4 acc[8];
    #pragma unroll
    for (int nt = 0; nt < 8; ++nt) {
        float bv = b1[nt * 16 + lm];
        acc[nt] = (f32x4){bv, bv, bv, bv};
    }
    int arow = wv * 16 + lm;
    #pragma unroll
    for (int kb = 0; kb < CH; kb += 32) {
        short8 afr = *(const short8*)&zs[arow * PQ + kb + 8 * lq];
        #pragma unroll
        for (int nt = 0; nt < 8; ++nt) {
            short8 bfr = *(const short8*)&ws[(nt * 16 + lm) * PQ + kb + 8 * lq];
            acc[nt] = __builtin_amdgcn_mfma_f32_16x16x32_bf16(afr, bfr, acc[nt], 0, 0, 0);
        }
    }
    __syncthreads();

    // scatter t (relu'd, bf16) into zs; stage w2T into ws
    #pragma unroll
    for (int nt = 0; nt < 8; ++nt)
        #pragma unroll
        for (int r = 0; r < 4; ++r) {
            float v = fmaxf(acc[nt][r], 0.f);
            zs[(wv * 16 + lq * 4 + r) * PQ + nt * 16 + lm] = f2bf(v);
        }
    for (int i = tid; i < CH * 16; i += 256) {
        int r = i >> 4, c = i & 15;
        *(uint4*)((char*)ws + r * (PQ * 2) + c * 16) = ((const uint4*)w2t)[i];
    }
    __syncthreads();

    // ---- matmul 2: h = t @ w2 + b2  [+ relu]
    #pragma unroll
    for (int nt = 0; nt < 8; ++nt) {
        float bv = b2[nt * 16 + lm];
        acc[nt] = (f32x4){bv, bv, bv, bv};
    }
    #pragma unroll
    for (int kb = 0; kb < CH; kb += 32) {
        short8 afr = *(const short8*)&zs[arow * PQ + kb + 8 * lq];
        #pragma unroll
        for (int nt = 0; nt < 8; ++nt) {
            short8 bfr = *(const short8*)&ws[(nt * 16 + lm) * PQ + kb + 8 * lq];
            acc[nt] = __builtin_amdgcn_mfma_f32_16x16x32_bf16(afr, bfr, acc[nt], 0, 0, 0);
        }
    }
    __syncthreads();

    #pragma unroll
    for (int nt = 0; nt < 8; ++nt)
        #pragma unroll
        for (int r = 0; r < 4; ++r) {
            float v = acc[nt][r];
            if (relu_out) v = fmaxf(v, 0.f);
            zs[(wv * 16 + lq * 4 + r) * PQ + nt * 16 + lm] = f2bf(v);
        }
    __syncthreads();

    if (!do_pool) {
        // coalesced h write-out
        for (int i = tid; i < BM * 16; i += 256) {
            int r = i >> 4, c = i & 15;
            int row = row0 + r;
            if (row < n)
                ((uint4*)hout)[row * 16 + c] = *(const uint4*)((char*)zs + r * (PQ * 2) + c * 16);
        }
    } else {
        // pool epilogue: per-graph partial sums from the LDS tile (batch sorted)
        int c2 = tid & 63;      // uint column (ch 2*c2, 2*c2+1)
        int rs = tid >> 6;      // 0..3
        float a0 = 0.f, a1 = 0.f;
        int prevg = -1;
        #pragma unroll
        for (int i = 0; i < BM / 4; ++i) {
            int r = rs + 4 * i;
            int row = row0 + r;
            if (row >= n) break;
            int g = batch[row];
            if (g != prevg) {
                if (prevg >= 0) {
                    atomicAdd(&pooled[prevg * CH + 2 * c2], a0);
                    atomicAdd(&pooled[prevg * CH + 2 * c2 + 1], a1);
                }
                prevg = g; a0 = 0.f; a1 = 0.f;
            }
            unsigned v = *(const unsigned*)((char*)zs + r * (PQ * 2) + c2 * 4);
            a0 += bflo(v); a1 += bfhi(v);
        }
        if (prevg >= 0) {
            atomicAdd(&pooled[prevg * CH + 2 * c2], a0);
            atomicAdd(&pooled[prevg * CH + 2 * c2 + 1], a1);
        }
    }
}

// ---------------------------------------------------------------- final linear

__global__ void final_linear_kernel(const float* __restrict__ pooled, const float* __restrict__ lin_w,
                                    const float* __restrict__ lin_b, float* __restrict__ out) {
    int g = blockIdx.x;
    int tid = threadIdx.x;   // 128
    __shared__ float pl[CH];
    pl[tid] = pooled[g * CH + tid];
    __syncthreads();
    if (tid < OUTC) {
        float a = lin_b[tid];
        #pragma unroll 16
        for (int c = 0; c < CH; ++c) a = fmaf(pl[c], lin_w[c * OUTC + tid], a);
        out[g * OUTC + tid] = a;
    }
}

// ---------------------------------------------------------------- launch

static inline size_t aln(size_t x) { return (x + 255) & ~size_t(255); }

extern "C" void kernel_launch(void* const* d_in, const int* in_sizes, int n_in,
                              void* d_out, int out_size, void* d_ws, size_t ws_size,
                              hipStream_t stream) {
    const float* x      = (const float*)d_in[0];
    const int*   ei     = (const int*)d_in[1];
    const int*   batch  = (const int*)d_in[2];
    const float* w1[3]  = {(const float*)d_in[3], (const float*)d_in[7],  (const float*)d_in[11]};
    const float* b1[3]  = {(const float*)d_in[4], (const float*)d_in[8],  (const float*)d_in[12]};
    const float* w2[3]  = {(const float*)d_in[5], (const float*)d_in[9],  (const float*)d_in[13]};
    const float* b2[3]  = {(const float*)d_in[6], (const float*)d_in[10], (const float*)d_in[14]};
    const float* lin_w  = (const float*)d_in[15];
    const float* lin_b  = (const float*)d_in[16];
    float* out = (float*)d_out;

    int E = in_sizes[1] / 2;
    int N = in_sizes[2];
    int n_graphs = out_size / OUTC;
    const int* src = ei;
    const int* dst = ei + E;

    char* p = (char*)d_ws;
    int* bucketCnt  = (int*)p; p += aln(NB * 4);
    int* bucketBase = (int*)p; p += aln(NB * 4);
    unsigned* pairs = (unsigned*)p; p += aln((size_t)NB * BCAP * 4);
    int* offs       = (int*)p; p += aln((size_t)(N + 1) * 4);
    int* csr        = (int*)p; p += aln((size_t)E * 4);
    unsigned short* xb = (unsigned short*)p; p += aln((size_t)N * CH * 2);
    unsigned short* hA = (unsigned short*)p; p += aln((size_t)N * CH * 2);
    unsigned short* hB = (unsigned short*)p; p += aln((size_t)N * CH * 2);
    float* pooled = (float*)p; p += aln((size_t)n_graphs * CH * 4);
    unsigned short* wt[6];
    for (int i = 0; i < 6; ++i) { wt[i] = (unsigned short*)p; p += aln((size_t)CH * CH * 2); }
    (void)ws_size; (void)n_in;

    // prep (independent of CSR)
    convert_x_kernel<<<(N * CH / 4 + 255) / 256, 256, 0, stream>>>((const float4*)x, (uint2*)xb, N * CH / 4);
    WPtrs wp;
    for (int l = 0; l < 3; ++l) {
        wp.s[2 * l] = w1[l];     wp.d[2 * l] = wt[2 * l];
        wp.s[2 * l + 1] = w2[l]; wp.d[2 * l + 1] = wt[2 * l + 1];
    }
    transpose_w_kernel<<<dim3(64, 6), 256, 0, stream>>>(wp);

    // CSR build: partition -> scan -> per-bucket build
    hipMemsetAsync(bucketCnt, 0, NB * 4, stream);
    partition_kernel<<<(E + PCHUNK - 1) / PCHUNK, 256, 0, stream>>>(src, dst, bucketCnt, pairs, E);
    scan_buckets_kernel<<<1, NB, 0, stream>>>(bucketCnt, bucketBase);
    build_csr_kernel<<<NB, 256, 0, stream>>>(pairs, bucketCnt, bucketBase, offs, csr, N);

    // pooled must be zeroed before layer-3 epilogue atomics
    hipMemsetAsync(pooled, 0, (size_t)n_graphs * CH * 4, stream);

    // fused layers
    int nblk = (N + BM - 1) / BM;
    gin_layer_kernel<<<nblk, 256, 0, stream>>>((const uint4*)xb, offs, csr,
        wt[0], b1[0], wt[1], b2[0], hA, batch, pooled, N, 1, 0);
    gin_layer_kernel<<<nblk, 256, 0, stream>>>((const uint4*)hA, offs, csr,
        wt[2], b1[1], wt[3], b2[1], hB, batch, pooled, N, 1, 0);
    gin_layer_kernel<<<nblk, 256, 0, stream>>>((const uint4*)hB, offs, csr,
        wt[4], b1[2], wt[5], b2[2], hA, batch, pooled, N, 0, 1);

    final_linear_kernel<<<n_graphs, CH, 0, stream>>>(pooled, lin_w, lin_b, out);
}

// Round 6
// 456.047 us; speedup vs baseline: 1.2042x; 1.2042x over previous
//
#include <hip/hip_runtime.h>

#define CH 128
#define OUTC 10
#define NB 256            // buckets (dst >> 9), only ceil(N/512) used
#define BCAP 10240        // per-bucket pair capacity (avg ~8192, >22 sigma margin)
#define PCHUNK 2048       // edges per partition block
#define PROWS 128         // rows per pool_partial block

typedef __attribute__((ext_vector_type(8))) short short8;
typedef __attribute__((ext_vector_type(4))) float f32x4;

// ---------------------------------------------------------------- helpers

__device__ inline unsigned short f2bf(float f) {
    unsigned u = __builtin_bit_cast(unsigned, f);
    u += 0x7fffu + ((u >> 16) & 1u);   // RNE
    return (unsigned short)(u >> 16);
}
__device__ inline float bflo(unsigned u) { return __builtin_bit_cast(float, u << 16); }
__device__ inline float bfhi(unsigned u) { return __builtin_bit_cast(float, u & 0xffff0000u); }

__device__ inline void acc8(float* a, const uint4& v) {
    a[0] += bflo(v.x); a[1] += bfhi(v.x);
    a[2] += bflo(v.y); a[3] += bfhi(v.y);
    a[4] += bflo(v.z); a[5] += bfhi(v.z);
    a[6] += bflo(v.w); a[7] += bfhi(v.w);
}

// ---------------------------------------------------------------- prep: x -> bf16

__global__ void convert_x_kernel(const float4* __restrict__ x4, uint2* __restrict__ xb, int n4) {
    int i = blockIdx.x * 256 + threadIdx.x;
    if (i < n4) {
        float4 v = x4[i];
        uint2 o;
        o.x = (unsigned)f2bf(v.x) | ((unsigned)f2bf(v.y) << 16);
        o.y = (unsigned)f2bf(v.z) | ((unsigned)f2bf(v.w) << 16);
        xb[i] = o;
    }
}

// ---------------------------------------------------------------- prep: weights -> bf16 transposed (wT[n][k])

struct WPtrs { const float* s[6]; unsigned short* d[6]; };

__global__ void transpose_w_kernel(WPtrs p) {
    int m = blockIdx.y;
    int i = blockIdx.x * 256 + threadIdx.x;
    int k = i >> 7;
    int nn = i & 127;
    p.d[m][nn * CH + k] = f2bf(p.s[m][i]);
}

// ---------------------------------------------------------------- CSR build, phase 1: partition edges into buckets

__global__ void partition_kernel(const int* __restrict__ src, const int* __restrict__ dst,
                                 int* __restrict__ bucketCnt, unsigned* __restrict__ pairs, int E) {
    __shared__ int hist[NB];
    __shared__ int base[NB];
    __shared__ int cur[NB];
    int tid = threadIdx.x;       // 256
    int e0 = blockIdx.x * PCHUNK;

    hist[tid] = 0;
    __syncthreads();
    #pragma unroll
    for (int i = 0; i < PCHUNK / 256; ++i) {
        int e = e0 + tid + i * 256;
        if (e < E) atomicAdd(&hist[dst[e] >> 9], 1);
    }
    __syncthreads();
    {
        int c = hist[tid];
        base[tid] = (c > 0) ? atomicAdd(&bucketCnt[tid], c) : 0;
        cur[tid] = 0;
    }
    __syncthreads();
    #pragma unroll
    for (int i = 0; i < PCHUNK / 256; ++i) {
        int e = e0 + tid + i * 256;
        if (e < E) {
            int d = dst[e];
            int bkt = d >> 9;
            int p = base[bkt] + atomicAdd(&cur[bkt], 1);
            if (p < BCAP)
                pairs[bkt * BCAP + p] = ((unsigned)(d & 511) << 17) | (unsigned)src[e];
        }
    }
}

__global__ void scan_buckets_kernel(const int* __restrict__ cnt, int* __restrict__ base) {
    __shared__ int sm[NB];
    int tid = threadIdx.x;
    sm[tid] = cnt[tid];
    __syncthreads();
    for (int off = 1; off < NB; off <<= 1) {
        int t = (tid >= off) ? sm[tid - off] : 0;
        __syncthreads();
        sm[tid] += t;
        __syncthreads();
    }
    base[tid] = sm[tid] - cnt[tid];
}

// ---------------------------------------------------------------- CSR build, phase 2

__launch_bounds__(256)
__global__ void build_csr_kernel(const unsigned* __restrict__ pairs, const int* __restrict__ bucketCnt,
                                 const int* __restrict__ bucketBase,
                                 int* __restrict__ offs, int* __restrict__ csr, int N) {
    __shared__ int ldeg[512];
    __shared__ int s0[512], s1[512];
    __shared__ int lexc[512];
    __shared__ int lcur[512];
    __shared__ int lcsr[BCAP];

    int b = blockIdx.x;
    int node0 = b << 9;
    if (node0 >= N) return;
    int nLocal = min(512, N - node0);
    int cnt = min(bucketCnt[b], BCAP);
    int gbase = bucketBase[b];
    int tid = threadIdx.x;   // 256

    for (int i = tid; i < 512; i += 256) ldeg[i] = 0;
    __syncthreads();
    for (int i = tid; i < cnt; i += 256)
        atomicAdd(&ldeg[pairs[b * BCAP + i] >> 17], 1);
    __syncthreads();

    for (int i = tid; i < 512; i += 256) s0[i] = ldeg[i];
    __syncthreads();
    int* sp = s0; int* dp = s1;
    for (int off = 1; off < 512; off <<= 1) {
        for (int i = tid; i < 512; i += 256)
            dp[i] = sp[i] + ((i >= off) ? sp[i - off] : 0);
        __syncthreads();
        int* t = sp; sp = dp; dp = t;
    }
    for (int i = tid; i < 512; i += 256) {
        int ex = sp[i] - ldeg[i];
        lexc[i] = ex;
        lcur[i] = ex;
    }
    __syncthreads();

    for (int i = tid; i < cnt; i += 256) {
        unsigned w = pairs[b * BCAP + i];
        int p = atomicAdd(&lcur[w >> 17], 1);
        lcsr[p] = (int)(w & 0x1ffffu);
    }
    __syncthreads();

    for (int i = tid; i < cnt; i += 256) csr[gbase + i] = lcsr[i];
    for (int i = tid; i < nLocal; i += 256) offs[node0 + i] = gbase + lexc[i];
    if (tid == 0 && node0 + nLocal == N) offs[N] = gbase + cnt;
}

// ---------------------------------------------------------------- aggregation (bf16, 4-edge unroll)
// z[i] = h[i] + sum_{e} h[src_e]; 16 lanes per node, per-layer template tag

template <int L>
__global__ void aggregate_kernel(const uint4* __restrict__ h4, const int* __restrict__ offs,
                                 const int* __restrict__ csr, uint4* __restrict__ z4, int n) {
    int node = blockIdx.x * 16 + (threadIdx.x >> 4);
    int lane = threadIdx.x & 15;
    if (node >= n) return;
    int beg = offs[node], end = offs[node + 1];

    float a[8];
    {
        uint4 self = h4[node * 16 + lane];
        a[0] = bflo(self.x); a[1] = bfhi(self.x);
        a[2] = bflo(self.y); a[3] = bfhi(self.y);
        a[4] = bflo(self.z); a[5] = bfhi(self.z);
        a[6] = bflo(self.w); a[7] = bfhi(self.w);
    }
    int e = beg;
    for (; e + 4 <= end; e += 4) {
        int s0 = csr[e], s1 = csr[e + 1], s2 = csr[e + 2], s3 = csr[e + 3];
        uint4 v0 = h4[s0 * 16 + lane];
        uint4 v1 = h4[s1 * 16 + lane];
        uint4 v2 = h4[s2 * 16 + lane];
        uint4 v3 = h4[s3 * 16 + lane];
        acc8(a, v0); acc8(a, v1); acc8(a, v2); acc8(a, v3);
    }
    for (; e < end; ++e) {
        uint4 v = h4[csr[e] * 16 + lane];
        acc8(a, v);
    }
    uint4 o;
    o.x = (unsigned)f2bf(a[0]) | ((unsigned)f2bf(a[1]) << 16);
    o.y = (unsigned)f2bf(a[2]) | ((unsigned)f2bf(a[3]) << 16);
    o.z = (unsigned)f2bf(a[4]) | ((unsigned)f2bf(a[5]) << 16);
    o.w = (unsigned)f2bf(a[6]) | ((unsigned)f2bf(a[7]) << 16);
    z4[node * 16 + lane] = o;
}

// ---------------------------------------------------------------- MFMA MLP: 128 rows/block, 512 threads, 8 waves

#define PQ 136
#define BM 128

template <int L>
__launch_bounds__(512, 2)
__global__ void mlp_mfma_kernel(const unsigned short* __restrict__ z,
                                const unsigned short* __restrict__ w1t, const float* __restrict__ b1,
                                const unsigned short* __restrict__ w2t, const float* __restrict__ b2,
                                unsigned short* __restrict__ hout, int n, int relu_out) {
    __shared__ __align__(16) unsigned short zs[BM * PQ];   // 34.8 KB
    __shared__ __align__(16) unsigned short ws[CH * PQ];   // 34.8 KB

    int tid = threadIdx.x;
    int row0 = blockIdx.x * BM;
    int wv = tid >> 6;        // 0..7
    int lane = tid & 63;
    int lm = lane & 15;
    int lq = lane >> 4;

    for (int i = tid; i < BM * 16; i += 512) {
        int r = i >> 4, c = i & 15;
        int row = row0 + r;
        uint4 v = (row < n) ? ((const uint4*)z)[row * 16 + c] : make_uint4(0, 0, 0, 0);
        *(uint4*)((char*)zs + r * (PQ * 2) + c * 16) = v;
    }
    for (int i = tid; i < CH * 16; i += 512) {
        int r = i >> 4, c = i & 15;
        *(uint4*)((char*)ws + r * (PQ * 2) + c * 16) = ((const uint4*)w1t)[i];
    }
    __syncthreads();

    // ---- matmul 1: t = relu(z @ w1 + b1)
    f32x4 acc[8];
    #pragma unroll
    for (int nt = 0; nt < 8; ++nt) {
        float bv = b1[nt * 16 + lm];
        acc[nt] = (f32x4){bv, bv, bv, bv};
    }
    int arow = wv * 16 + lm;
    #pragma unroll
    for (int kb = 0; kb < CH; kb += 32) {
        short8 afr = *(const short8*)&zs[arow * PQ + kb + 8 * lq];
        #pragma unroll
        for (int nt = 0; nt < 8; ++nt) {
            short8 bfr = *(const short8*)&ws[(nt * 16 + lm) * PQ + kb + 8 * lq];
            acc[nt] = __builtin_amdgcn_mfma_f32_16x16x32_bf16(afr, bfr, acc[nt], 0, 0, 0);
        }
    }
    __syncthreads();

    // scatter t (relu'd, bf16) into zs; stage w2T into ws
    #pragma unroll
    for (int nt = 0; nt < 8; ++nt)
        #pragma unroll
        for (int r = 0; r < 4; ++r) {
            float v = fmaxf(acc[nt][r], 0.f);
            zs[(wv * 16 + lq * 4 + r) * PQ + nt * 16 + lm] = f2bf(v);
        }
    for (int i = tid; i < CH * 16; i += 512) {
        int r = i >> 4, c = i & 15;
        *(uint4*)((char*)ws + r * (PQ * 2) + c * 16) = ((const uint4*)w2t)[i];
    }
    __syncthreads();

    // ---- matmul 2: h = t @ w2 + b2  [+ relu]
    #pragma unroll
    for (int nt = 0; nt < 8; ++nt) {
        float bv = b2[nt * 16 + lm];
        acc[nt] = (f32x4){bv, bv, bv, bv};
    }
    #pragma unroll
    for (int kb = 0; kb < CH; kb += 32) {
        short8 afr = *(const short8*)&zs[arow * PQ + kb + 8 * lq];
        #pragma unroll
        for (int nt = 0; nt < 8; ++nt) {
            short8 bfr = *(const short8*)&ws[(nt * 16 + lm) * PQ + kb + 8 * lq];
            acc[nt] = __builtin_amdgcn_mfma_f32_16x16x32_bf16(afr, bfr, acc[nt], 0, 0, 0);
        }
    }
    __syncthreads();

    #pragma unroll
    for (int nt = 0; nt < 8; ++nt)
        #pragma unroll
        for (int r = 0; r < 4; ++r) {
            float v = acc[nt][r];
            if (relu_out) v = fmaxf(v, 0.f);
            zs[(wv * 16 + lq * 4 + r) * PQ + nt * 16 + lm] = f2bf(v);
        }
    __syncthreads();

    for (int i = tid; i < BM * 16; i += 512) {
        int r = i >> 4, c = i & 15;
        int row = row0 + r;
        if (row < n)
            ((uint4*)hout)[row * 16 + c] = *(const uint4*)((char*)zs + r * (PQ * 2) + c * 16);
    }
}

// ---------------------------------------------------------------- pooling

__global__ void pool_partial_kernel(const unsigned* __restrict__ h2, const int* __restrict__ batch,
                                    float* __restrict__ pooled, int n) {
    int r0 = blockIdx.x * PROWS;
    int tid = threadIdx.x;          // 256
    int c2 = tid & 63;
    int rs = tid >> 6;
    float a0 = 0.f, a1 = 0.f;
    int prevg = -1;
    #pragma unroll 4
    for (int i = 0; i < PROWS / 4; ++i) {
        int r = r0 + rs + i * 4;
        if (r >= n) break;
        int g = batch[r];
        if (g != prevg) {
            if (prevg >= 0) {
                atomicAdd(&pooled[prevg * CH + 2 * c2], a0);
                atomicAdd(&pooled[prevg * CH + 2 * c2 + 1], a1);
            }
            prevg = g; a0 = 0.f; a1 = 0.f;
        }
        unsigned v = h2[r * 64 + c2];
        a0 += bflo(v); a1 += bfhi(v);
    }
    if (prevg >= 0) {
        atomicAdd(&pooled[prevg * CH + 2 * c2], a0);
        atomicAdd(&pooled[prevg * CH + 2 * c2 + 1], a1);
    }
}

__global__ void final_linear_kernel(const float* __restrict__ pooled, const float* __restrict__ lin_w,
                                    const float* __restrict__ lin_b, float* __restrict__ out) {
    int g = blockIdx.x;
    int tid = threadIdx.x;   // 128
    __shared__ float pl[CH];
    pl[tid] = pooled[g * CH + tid];
    __syncthreads();
    if (tid < OUTC) {
        float a = lin_b[tid];
        #pragma unroll 16
        for (int c = 0; c < CH; ++c) a = fmaf(pl[c], lin_w[c * OUTC + tid], a);
        out[g * OUTC + tid] = a;
    }
}

// ---------------------------------------------------------------- launch

static inline size_t aln(size_t x) { return (x + 255) & ~size_t(255); }

extern "C" void kernel_launch(void* const* d_in, const int* in_sizes, int n_in,
                              void* d_out, int out_size, void* d_ws, size_t ws_size,
                              hipStream_t stream) {
    const float* x      = (const float*)d_in[0];
    const int*   ei     = (const int*)d_in[1];
    const int*   batch  = (const int*)d_in[2];
    const float* w1[3]  = {(const float*)d_in[3], (const float*)d_in[7],  (const float*)d_in[11]};
    const float* b1[3]  = {(const float*)d_in[4], (const float*)d_in[8],  (const float*)d_in[12]};
    const float* w2[3]  = {(const float*)d_in[5], (const float*)d_in[9],  (const float*)d_in[13]};
    const float* b2[3]  = {(const float*)d_in[6], (const float*)d_in[10], (const float*)d_in[14]};
    const float* lin_w  = (const float*)d_in[15];
    const float* lin_b  = (const float*)d_in[16];
    float* out = (float*)d_out;

    int E = in_sizes[1] / 2;
    int N = in_sizes[2];
    int n_graphs = out_size / OUTC;
    const int* src = ei;
    const int* dst = ei + E;

    char* p = (char*)d_ws;
    int* bucketCnt  = (int*)p; p += aln(NB * 4);
    int* bucketBase = (int*)p; p += aln(NB * 4);
    unsigned* pairs = (unsigned*)p; p += aln((size_t)NB * BCAP * 4);
    int* offs       = (int*)p; p += aln((size_t)(N + 1) * 4);
    int* csr        = (int*)p; p += aln((size_t)E * 4);
    unsigned short* xb = (unsigned short*)p; p += aln((size_t)N * CH * 2);
    unsigned short* zb = (unsigned short*)p; p += aln((size_t)N * CH * 2);
    unsigned short* hA = (unsigned short*)p; p += aln((size_t)N * CH * 2);
    unsigned short* hB = (unsigned short*)p; p += aln((size_t)N * CH * 2);
    float* pooled = (float*)p; p += aln((size_t)n_graphs * CH * 4);
    unsigned short* wt[6];
    for (int i = 0; i < 6; ++i) { wt[i] = (unsigned short*)p; p += aln((size_t)CH * CH * 2); }
    (void)ws_size; (void)n_in;

    // prep
    convert_x_kernel<<<(N * CH / 4 + 255) / 256, 256, 0, stream>>>((const float4*)x, (uint2*)xb, N * CH / 4);
    WPtrs wp;
    for (int l = 0; l < 3; ++l) {
        wp.s[2 * l] = w1[l];     wp.d[2 * l] = wt[2 * l];
        wp.s[2 * l + 1] = w2[l]; wp.d[2 * l + 1] = wt[2 * l + 1];
    }
    transpose_w_kernel<<<dim3(64, 6), 256, 0, stream>>>(wp);

    // CSR build
    hipMemsetAsync(bucketCnt, 0, NB * 4, stream);
    partition_kernel<<<(E + PCHUNK - 1) / PCHUNK, 256, 0, stream>>>(src, dst, bucketCnt, pairs, E);
    scan_buckets_kernel<<<1, NB, 0, stream>>>(bucketCnt, bucketBase);
    build_csr_kernel<<<NB, 256, 0, stream>>>(pairs, bucketCnt, bucketBase, offs, csr, N);

    int ablk = (N + 15) / 16;
    int mblk = (N + BM - 1) / BM;

    // layer 0
    aggregate_kernel<0><<<ablk, 256, 0, stream>>>((const uint4*)xb, offs, csr, (uint4*)zb, N);
    mlp_mfma_kernel<0><<<mblk, 512, 0, stream>>>(zb, wt[0], b1[0], wt[1], b2[0], hA, N, 1);
    // layer 1
    aggregate_kernel<1><<<ablk, 256, 0, stream>>>((const uint4*)hA, offs, csr, (uint4*)zb, N);
    mlp_mfma_kernel<1><<<mblk, 512, 0, stream>>>(zb, wt[2], b1[1], wt[3], b2[1], hB, N, 1);
    // layer 2
    aggregate_kernel<2><<<ablk, 256, 0, stream>>>((const uint4*)hB, offs, csr, (uint4*)zb, N);
    mlp_mfma_kernel<2><<<mblk, 512, 0, stream>>>(zb, wt[4], b1[2], wt[5], b2[2], hA, N, 0);

    // pooling + classifier
    hipMemsetAsync(pooled, 0, (size_t)n_graphs * CH * 4, stream);
    pool_partial_kernel<<<(N + PROWS - 1) / PROWS, 256, 0, stream>>>(
        (const unsigned*)hA, batch, pooled, N);
    final_linear_kernel<<<n_graphs, CH, 0, stream>>>(pooled, lin_w, lin_b, out);
}